// Round 6
// baseline (1040.023 us; speedup 1.0000x reference)
//
#include <hip/hip_runtime.h>

// ---------------------------------------------------------------------------
// GIN 3-layer: h_{l+1} = act((h + agg(h)) @ W + b)
// Restructured: z = act(h) @ W ; a = b + z + agg(z)   (agg commutes with W)
// z stored BF16; fp32 register aggregation; split-bf16 MFMA GEMM.
// Layers 2,3 fused (gather -> MFMA A-fragment regs, no LDS).
// NEW: nodes processed in degree-sorted order (counting sort) so each wave's
// 16 rows have equal degree -> gather loop trip = deg, not max16(deg).
// ---------------------------------------------------------------------------

typedef __attribute__((ext_vector_type(8))) short short8;
typedef __attribute__((ext_vector_type(4))) float f32x4;
typedef unsigned short ushort_t;
typedef unsigned int uint_t;

__device__ inline ushort_t bf16_rne(float f) {
  uint_t u = __float_as_uint(f);
  uint_t r = (u + 0x7FFFu + ((u >> 16) & 1u)) >> 16;
  return (ushort_t)r;
}
__device__ inline float bf16_to_f32(ushort_t h) {
  return __uint_as_float(((uint_t)h) << 16);
}

// ---- edge dtype detection: int64 (reference decl) vs int32 (JAX x64-off) ----
__global__ __launch_bounds__(256) void k_detect(const int* __restrict__ ew,
                                                int* __restrict__ flag, int E) {
  int i = blockIdx.x * 256 + threadIdx.x;
  int idx = 2 * i + 1;
  if (idx < 2 * E) {
    if (ew[idx] != 0) atomicOr(flag, 1);    // nonzero odd word => int32 layout
  }
}

// ---- CSR build (reads edges directly, no staging) ---------------------------
__global__ __launch_bounds__(256) void k_hist(const void* __restrict__ edges,
                                              const int* __restrict__ flag,
                                              int* __restrict__ counts, int E) {
  int e = blockIdx.x * 256 + threadIdx.x;
  if (e >= E) return;
  int d;
  if (*flag) d = ((const int*)edges)[E + e];
  else       d = (int)((const long long*)edges)[E + e];
  atomicAdd(&counts[d], 1);
}

// ---- degree counting sort: histogram over degree bins -> scan -> scatter ----
__global__ __launch_bounds__(256) void k_deghist(const int* __restrict__ counts,
                                                 int* __restrict__ degcnt, int N) {
  int i = blockIdx.x * 256 + threadIdx.x;
  if (i < N) atomicAdd(&degcnt[min(counts[i], 255)], 1);
}

__global__ __launch_bounds__(256) void k_degscan(int* __restrict__ degcnt) {
  __shared__ int s[256];
  int t = threadIdx.x;
  int v = degcnt[t];
  s[t] = v;
  __syncthreads();
  for (int d = 1; d < 256; d <<= 1) {
    int u = (t >= d) ? s[t - d] : 0;
    __syncthreads();
    s[t] += u;
    __syncthreads();
  }
  degcnt[t] = s[t] - v;   // exclusive offsets; reused as cursors
}

__global__ __launch_bounds__(256) void k_degscatter(const int* __restrict__ counts,
                                                    int* __restrict__ degcur,
                                                    int* __restrict__ perm, int N) {
  int i = blockIdx.x * 256 + threadIdx.x;
  if (i >= N) return;
  int d = min(counts[i], 255);
  int pos = atomicAdd(&degcur[d], 1);
  perm[pos] = i;
}

__global__ __launch_bounds__(256) void k_scan1(const int* __restrict__ counts,
                                               int* __restrict__ offs,
                                               int* __restrict__ bsum, int N) {
  __shared__ int s[256];
  int t = threadIdx.x;
  int base = blockIdx.x * 1024 + t * 4;
  int c0 = 0, c1 = 0, c2 = 0, c3 = 0;
  if (base + 0 < N) c0 = counts[base + 0];
  if (base + 1 < N) c1 = counts[base + 1];
  if (base + 2 < N) c2 = counts[base + 2];
  if (base + 3 < N) c3 = counts[base + 3];
  int mySum = c0 + c1 + c2 + c3;
  s[t] = mySum;
  __syncthreads();
  for (int d = 1; d < 256; d <<= 1) {
    int v = (t >= d) ? s[t - d] : 0;
    __syncthreads();
    s[t] += v;
    __syncthreads();
  }
  int excl = s[t] - mySum;
  if (base + 0 < N) offs[base + 0] = excl;
  if (base + 1 < N) offs[base + 1] = excl + c0;
  if (base + 2 < N) offs[base + 2] = excl + c0 + c1;
  if (base + 3 < N) offs[base + 3] = excl + c0 + c1 + c2;
  if (t == 255) bsum[blockIdx.x] = s[255];
}

__global__ __launch_bounds__(128) void k_scan2(int* __restrict__ bsum, int nb) {
  __shared__ int s[128];
  int t = threadIdx.x;
  int v = (t < nb) ? bsum[t] : 0;
  s[t] = v;
  __syncthreads();
  for (int d = 1; d < 128; d <<= 1) {
    int u = (t >= d) ? s[t - d] : 0;
    __syncthreads();
    s[t] += u;
    __syncthreads();
  }
  if (t < nb) bsum[t] = s[t] - v;
}

__global__ __launch_bounds__(256) void k_scan3(int* __restrict__ offs,
                                               const int* __restrict__ bsum,
                                               int* __restrict__ cursor,
                                               int N, int E) {
  int t = threadIdx.x;
  int add = bsum[blockIdx.x];
  int base = blockIdx.x * 1024 + t * 4;
#pragma unroll
  for (int j = 0; j < 4; j++) {
    int i = base + j;
    if (i < N) { int v = offs[i] + add; offs[i] = v; cursor[i] = v; }
  }
  if (blockIdx.x == 0 && t == 0) offs[N] = E;
}

__global__ __launch_bounds__(256) void k_fill(const void* __restrict__ edges,
                                              const int* __restrict__ flag,
                                              int* __restrict__ cursor,
                                              int* __restrict__ csr, int E) {
  int e = blockIdx.x * 256 + threadIdx.x;
  if (e >= E) return;
  int s, d;
  if (*flag) {
    const int* p = (const int*)edges;
    s = p[e]; d = p[E + e];
  } else {
    const long long* p = (const long long*)edges;
    s = (int)p[e]; d = (int)p[E + e];
  }
  int pos = atomicAdd(&cursor[d], 1);
  csr[pos] = s;
}

// ---- W repack into MFMA B-fragment order (hi/lo split bf16) -----------------
__global__ __launch_bounds__(256) void k_repack(
    const float* __restrict__ W1, const float* __restrict__ W2,
    const float* __restrict__ W3,
    ushort_t* __restrict__ h1, ushort_t* __restrict__ l1,
    ushort_t* __restrict__ h2, ushort_t* __restrict__ l2,
    ushort_t* __restrict__ h3, ushort_t* __restrict__ l3) {
  int idx = blockIdx.x * 256 + threadIdx.x;
  const float* W; ushort_t* H; ushort_t* L; int NC; int i;
  if (idx < 16384)      { W = W1; H = h1; L = l1; NC = 128; i = idx; }
  else if (idx < 32768) { W = W2; H = h2; L = l2; NC = 128; i = idx - 16384; }
  else if (idx < 40960) { W = W3; H = h3; L = l3; NC = 64;  i = idx - 32768; }
  else return;
  int j = i & 7;
  int lane = (i >> 3) & 63;
  int NT = NC >> 4;
  int tile = (i >> 9) & (NT - 1);
  int ks = i >> (9 + (NC == 128 ? 3 : 2));
  int k = ks * 32 + (lane >> 4) * 8 + j;
  int n = tile * 16 + (lane & 15);
  float v = W[(size_t)k * NC + n];
  ushort_t hi = bf16_rne(v);
  ushort_t lo = bf16_rne(v - bf16_to_f32(hi));
  H[i] = hi; L[i] = lo;
}

// ---- layer 1 GEMM: Z(bf16)[M x NC] = A(fp32)[M x 128] @ W -------------------
template <int NC>
__global__ __launch_bounds__(256) void k_gemm_mfma(
    const float* __restrict__ A, const ushort_t* __restrict__ Bhi,
    const ushort_t* __restrict__ Blo, ushort_t* __restrict__ Z, int M) {
  constexpr int NT = NC / 16;
  int lane = threadIdx.x & 63;
  int wave = threadIdx.x >> 6;
  int row0 = blockIdx.x * 64 + wave * 16;
  int m = lane & 15;
  int q = lane >> 4;
  int grow = row0 + m;
  bool rowok = (grow < M);

  f32x4 acc[NT];
#pragma unroll
  for (int t = 0; t < NT; t++) { acc[t][0] = 0.f; acc[t][1] = 0.f; acc[t][2] = 0.f; acc[t][3] = 0.f; }

  const float* arow = A + (size_t)(rowok ? grow : 0) * 128 + q * 8;

#pragma unroll
  for (int ks = 0; ks < 4; ks++) {
    float av[8];
    *(float4*)(av)     = *(const float4*)(arow + ks * 32);
    *(float4*)(av + 4) = *(const float4*)(arow + ks * 32 + 4);
    short8 ahi, alo;
#pragma unroll
    for (int j = 0; j < 8; j++) {
      float v = av[j];
      ushort_t hi = bf16_rne(v);
      ahi[j] = (short)hi;
      alo[j] = (short)bf16_rne(v - bf16_to_f32(hi));
    }
#pragma unroll
    for (int t = 0; t < NT; t++) {
      const short8 bh = *(const short8*)(Bhi + (((size_t)ks * NT + t) * 64 + lane) * 8);
      const short8 bl = *(const short8*)(Blo + (((size_t)ks * NT + t) * 64 + lane) * 8);
      acc[t] = __builtin_amdgcn_mfma_f32_16x16x32_bf16(ahi, bh, acc[t], 0, 0, 0);
      acc[t] = __builtin_amdgcn_mfma_f32_16x16x32_bf16(ahi, bl, acc[t], 0, 0, 0);
      acc[t] = __builtin_amdgcn_mfma_f32_16x16x32_bf16(alo, bh, acc[t], 0, 0, 0);
    }
  }

  int zrow = row0 + q * 4;
#pragma unroll
  for (int r = 0; r < 4; r++) {
    if (zrow + r < M) {
#pragma unroll
      for (int t = 0; t < NT; t++)
        Z[(size_t)(zrow + r) * NC + t * 16 + m] = bf16_rne(acc[t][r]);
    }
  }
}

// ---- fused agg + GEMM (layers 2,3): degree-sorted via perm ------------------
// Lane (m, q) handles node perm[row0+m]; aggregates a[.][ks*32+q*8+j] in fp32
// regs from bf16 z rows, then relu + hi/lo split + MFMA. z stays in ORIGINAL
// node order (gather indices are original ids); only processing order permuted.
template <int NC>
__global__ __launch_bounds__(256, 4) void k_fused(
    const ushort_t* __restrict__ Zin, const int* __restrict__ csr,
    const int* __restrict__ offs, const int* __restrict__ perm,
    const float* __restrict__ bias,
    const ushort_t* __restrict__ Bhi, const ushort_t* __restrict__ Blo,
    ushort_t* __restrict__ Zout, int M) {
  constexpr int NT = NC / 16;
  int lane = threadIdx.x & 63;
  int wave = threadIdx.x >> 6;
  int row0 = blockIdx.x * 64 + wave * 16;
  int m = lane & 15;
  int q = lane >> 4;
  int srow = row0 + m;                        // sorted index
  bool rowok = (srow < M);
  int node = perm[rowok ? srow : 0];          // original node id

  // accumulators a[node][ks*32 + q*8 + j], init = bias + Zin[node]
  float av[4][8];
  const ushort_t* zr0 = Zin + (size_t)node * 128 + q * 8;
  const float* bq = bias + q * 8;
#pragma unroll
  for (int ks = 0; ks < 4; ks++) {
    float4 b0 = *(const float4*)(bq + ks * 32);
    float4 b1 = *(const float4*)(bq + ks * 32 + 4);
    short8 u = *(const short8*)(zr0 + ks * 32);
    av[ks][0] = b0.x + bf16_to_f32((ushort_t)u[0]);
    av[ks][1] = b0.y + bf16_to_f32((ushort_t)u[1]);
    av[ks][2] = b0.z + bf16_to_f32((ushort_t)u[2]);
    av[ks][3] = b0.w + bf16_to_f32((ushort_t)u[3]);
    av[ks][4] = b1.x + bf16_to_f32((ushort_t)u[4]);
    av[ks][5] = b1.y + bf16_to_f32((ushort_t)u[5]);
    av[ks][6] = b1.z + bf16_to_f32((ushort_t)u[6]);
    av[ks][7] = b1.w + bf16_to_f32((ushort_t)u[7]);
  }

  int s = 0, e = 0;
  if (rowok) { s = offs[node]; e = offs[node + 1]; }
  int j = s;
  for (; j + 2 <= e; j += 2) {
    int i0 = csr[j], i1 = csr[j + 1];
    const ushort_t* za = Zin + (size_t)i0 * 128 + q * 8;
    const ushort_t* zb = Zin + (size_t)i1 * 128 + q * 8;
    short8 ua[4], ub[4];
#pragma unroll
    for (int ks = 0; ks < 4; ks++) ua[ks] = *(const short8*)(za + ks * 32);
#pragma unroll
    for (int ks = 0; ks < 4; ks++) ub[ks] = *(const short8*)(zb + ks * 32);
#pragma unroll
    for (int ks = 0; ks < 4; ks++)
#pragma unroll
      for (int jj = 0; jj < 8; jj++)
        av[ks][jj] += bf16_to_f32((ushort_t)ua[ks][jj]) +
                      bf16_to_f32((ushort_t)ub[ks][jj]);
  }
  if (j < e) {
    int i0 = csr[j];
    const ushort_t* za = Zin + (size_t)i0 * 128 + q * 8;
#pragma unroll
    for (int ks = 0; ks < 4; ks++) {
      short8 u = *(const short8*)(za + ks * 32);
#pragma unroll
      for (int jj = 0; jj < 8; jj++)
        av[ks][jj] += bf16_to_f32((ushort_t)u[jj]);
    }
  }

  // relu + split-bf16 + MFMA
  f32x4 acc[NT];
#pragma unroll
  for (int tt = 0; tt < NT; tt++) { acc[tt][0] = 0.f; acc[tt][1] = 0.f; acc[tt][2] = 0.f; acc[tt][3] = 0.f; }

#pragma unroll
  for (int ks = 0; ks < 4; ks++) {
    short8 ahi, alo;
#pragma unroll
    for (int jj = 0; jj < 8; jj++) {
      float v = fmaxf(av[ks][jj], 0.f);
      ushort_t hi = bf16_rne(v);
      ahi[jj] = (short)hi;
      alo[jj] = (short)bf16_rne(v - bf16_to_f32(hi));
    }
#pragma unroll
    for (int tt = 0; tt < NT; tt++) {
      const short8 bh = *(const short8*)(Bhi + (((size_t)ks * NT + tt) * 64 + lane) * 8);
      const short8 bl = *(const short8*)(Blo + (((size_t)ks * NT + tt) * 64 + lane) * 8);
      acc[tt] = __builtin_amdgcn_mfma_f32_16x16x32_bf16(ahi, bh, acc[tt], 0, 0, 0);
      acc[tt] = __builtin_amdgcn_mfma_f32_16x16x32_bf16(ahi, bl, acc[tt], 0, 0, 0);
      acc[tt] = __builtin_amdgcn_mfma_f32_16x16x32_bf16(alo, bh, acc[tt], 0, 0, 0);
    }
  }

  // store: D row r of this lane corresponds to sorted index row0 + q*4 + r
  int sbase = row0 + q * 4;
#pragma unroll
  for (int r = 0; r < 4; r++) {
    if (sbase + r < M) {
      int prow = perm[sbase + r];
#pragma unroll
      for (int tt = 0; tt < NT; tt++)
        Zout[(size_t)prow * NC + tt * 16 + m] = bf16_rne(acc[tt][r]);
    }
  }
}

// ---- final agg (64 cols, bf16 z in, fp32 out), degree-sorted ----------------
__global__ __launch_bounds__(256) void k_agg64(const ushort_t* __restrict__ z,
                                               const int* __restrict__ csr,
                                               const int* __restrict__ offs,
                                               const int* __restrict__ perm,
                                               const float* __restrict__ bias,
                                               float* __restrict__ out, int N) {
  int t = threadIdx.x;
  int si = blockIdx.x * 32 + (t >> 3);
  if (si >= N) return;
  int node = perm[si];
  int c = (t & 7) * 8;
  float acc[8];
  {
    short8 u = *(const short8*)(z + (size_t)node * 64 + c);
#pragma unroll
    for (int jj = 0; jj < 8; jj++)
      acc[jj] = bias[c + jj] + bf16_to_f32((ushort_t)u[jj]);
  }
  int s = offs[node], e = offs[node + 1];
  int j = s;
  for (; j + 4 <= e; j += 4) {
    int i0 = csr[j], i1 = csr[j + 1], i2 = csr[j + 2], i3 = csr[j + 3];
    short8 u0 = *(const short8*)(z + (size_t)i0 * 64 + c);
    short8 u1 = *(const short8*)(z + (size_t)i1 * 64 + c);
    short8 u2 = *(const short8*)(z + (size_t)i2 * 64 + c);
    short8 u3 = *(const short8*)(z + (size_t)i3 * 64 + c);
#pragma unroll
    for (int jj = 0; jj < 8; jj++)
      acc[jj] += (bf16_to_f32((ushort_t)u0[jj]) + bf16_to_f32((ushort_t)u1[jj])) +
                 (bf16_to_f32((ushort_t)u2[jj]) + bf16_to_f32((ushort_t)u3[jj]));
  }
  for (; j < e; j++) {
    int i0 = csr[j];
    short8 u = *(const short8*)(z + (size_t)i0 * 64 + c);
#pragma unroll
    for (int jj = 0; jj < 8; jj++)
      acc[jj] += bf16_to_f32((ushort_t)u[jj]);
  }
  float4 o0 = make_float4(acc[0], acc[1], acc[2], acc[3]);
  float4 o1 = make_float4(acc[4], acc[5], acc[6], acc[7]);
  *(float4*)&out[(size_t)node * 64 + c]     = o0;
  *(float4*)&out[(size_t)node * 64 + c + 4] = o1;
}

// ---------------------------------------------------------------------------
extern "C" void kernel_launch(void* const* d_in, const int* in_sizes, int n_in,
                              void* d_out, int out_size, void* d_ws, size_t ws_size,
                              hipStream_t stream) {
  const float* x  = (const float*)d_in[0];
  const void* edges = d_in[1];
  const float* W1 = (const float*)d_in[2];
  const float* b1 = (const float*)d_in[3];
  const float* W2 = (const float*)d_in[4];
  const float* b2 = (const float*)d_in[5];
  const float* W3 = (const float*)d_in[6];
  const float* b3 = (const float*)d_in[7];
  float* out = (float*)d_out;

  int N = in_sizes[0] / 128;   // 100000
  int E = in_sizes[1] / 2;     // 600000

  char* w = (char*)d_ws;
  size_t off = 0;
  auto alloc = [&](size_t bytes) -> void* {
    void* p = w + off;
    off = (off + bytes + 255) & ~(size_t)255;
    return p;
  };
  size_t curBytes = ((size_t)N * 4 + 255) & ~(size_t)255;
  // cursor + flag + degcnt are contiguous -> one memset zeroes all three
  int*   cursor = (int*)alloc(curBytes);     // degree counts, then fill cursor
  int*   flag   = (int*)alloc(4);
  int*   degcnt = (int*)alloc(1024);         // 256 degree bins
  int*   csr    = (int*)alloc((size_t)E * 4);
  int*   offs   = (int*)alloc((size_t)(N + 1) * 4);
  int*   perm   = (int*)alloc((size_t)N * 4);
  int*   bsum   = (int*)alloc(4096);
  ushort_t* h1  = (ushort_t*)alloc(16384 * 2);
  ushort_t* l1  = (ushort_t*)alloc(16384 * 2);
  ushort_t* h2  = (ushort_t*)alloc(16384 * 2);
  ushort_t* l2  = (ushort_t*)alloc(16384 * 2);
  ushort_t* h3  = (ushort_t*)alloc(8192 * 2);
  ushort_t* l3  = (ushort_t*)alloc(8192 * 2);
  ushort_t* z1  = (ushort_t*)alloc((size_t)N * 128 * 2);  // bf16
  ushort_t* z2  = (ushort_t*)alloc((size_t)N * 128 * 2);  // bf16
  ushort_t* z3  = z1;                                     // reuse (N x 64 fits)

  int ge = (E + 255) / 256;
  int gn = (N + 255) / 256;
  int nb = (N + 1023) / 1024;

  hipMemsetAsync(cursor, 0, curBytes + 256 + 1024, stream);
  k_detect<<<4, 256, 0, stream>>>((const int*)edges, flag, E);
  k_hist<<<ge, 256, 0, stream>>>(edges, flag, cursor, E);
  // degree counting sort (reads cursor=counts BEFORE scan3 overwrites it)
  k_deghist<<<gn, 256, 0, stream>>>(cursor, degcnt, N);
  k_degscan<<<1, 256, 0, stream>>>(degcnt);
  k_degscatter<<<gn, 256, 0, stream>>>(cursor, degcnt, perm, N);
  // CSR offsets + fill
  k_scan1<<<nb, 256, 0, stream>>>(cursor, offs, bsum, N);
  k_scan2<<<1, 128, 0, stream>>>(bsum, nb);
  k_scan3<<<nb, 256, 0, stream>>>(offs, bsum, cursor, N, E);
  k_fill<<<ge, 256, 0, stream>>>(edges, flag, cursor, csr, E);
  k_repack<<<160, 256, 0, stream>>>(W1, W2, W3, h1, l1, h2, l2, h3, l3);

  int gm = (N + 63) / 64;
  // layer 1: z1 = x @ W1   (bf16 out, natural order)
  k_gemm_mfma<128><<<gm, 256, 0, stream>>>(x, h1, l1, z1, N);
  // layer 2 fused: a1 = b1 + z1 + agg(z1) (regs); z2 = relu(a1) @ W2
  k_fused<128><<<gm, 256, 0, stream>>>(z1, csr, offs, perm, b1, h2, l2, z2, N);
  // layer 3 fused: a2 = b2 + z2 + agg(z2) (regs); z3 = relu(a2) @ W3
  k_fused<64><<<gm, 256, 0, stream>>>(z2, csr, offs, perm, b2, h3, l3, z3, N);
  // final agg: out = b3 + z3 + agg(z3)   (fp32 out)
  k_agg64<<<(N + 31) / 32, 256, 0, stream>>>(z3, csr, offs, perm, b3, out, N);
}

// Round 7
// 319.134 us; speedup vs baseline: 3.2589x; 3.2589x over previous
//
#include <hip/hip_runtime.h>

// ---------------------------------------------------------------------------
// GIN 3-layer: h_{l+1} = act((h + agg(h)) @ W + b)
// Restructured: z = act(h) @ W ; a = b + z + agg(z)   (agg commutes with W)
// z stored BF16; fp32 register aggregation; split-bf16 MFMA GEMM.
// Layers 2,3 fused (gather -> MFMA A-fragment regs, no LDS).
// Nodes processed in degree-sorted order; counting sort built with
// ZERO global atomics (per-block LDS hist -> 2-level scan -> rank scatter).
// ---------------------------------------------------------------------------

typedef __attribute__((ext_vector_type(8))) short short8;
typedef __attribute__((ext_vector_type(4))) float f32x4;
typedef unsigned short ushort_t;
typedef unsigned int uint_t;

__device__ inline ushort_t bf16_rne(float f) {
  uint_t u = __float_as_uint(f);
  uint_t r = (u + 0x7FFFu + ((u >> 16) & 1u)) >> 16;
  return (ushort_t)r;
}
__device__ inline float bf16_to_f32(ushort_t h) {
  return __uint_as_float(((uint_t)h) << 16);
}

// ---- edge dtype detection: int64 (reference decl) vs int32 (JAX x64-off) ----
__global__ __launch_bounds__(256) void k_detect(const int* __restrict__ ew,
                                                int* __restrict__ flag, int E) {
  int i = blockIdx.x * 256 + threadIdx.x;
  int idx = 2 * i + 1;
  if (idx < 2 * E) {
    if (ew[idx] != 0) atomicOr(flag, 1);    // nonzero odd word => int32 layout
  }
}

// ---- degree histogram (per-node in-degree counts) ---------------------------
__global__ __launch_bounds__(256) void k_hist(const void* __restrict__ edges,
                                              const int* __restrict__ flag,
                                              int* __restrict__ counts, int E) {
  int e = blockIdx.x * 256 + threadIdx.x;
  if (e >= E) return;
  int d;
  if (*flag) d = ((const int*)edges)[E + e];
  else       d = (int)((const long long*)edges)[E + e];
  atomicAdd(&counts[d], 1);   // 100k distinct counters -> low contention
}

// ---- counting sort by degree, no global atomics -----------------------------
// 1) per-block LDS histogram -> blockhist[bin * nb2 + blk]
__global__ __launch_bounds__(256) void k_blockhist(const int* __restrict__ counts,
                                                   int* __restrict__ blockhist,
                                                   int N, int nb2) {
  __shared__ int h[256];
  int t = threadIdx.x;
  h[t] = 0;
  __syncthreads();
  int i = blockIdx.x * 256 + t;
  if (i < N) atomicAdd(&h[min(counts[i], 255)], 1);
  __syncthreads();
  blockhist[t * nb2 + blockIdx.x] = h[t];
}

// 2) per-bin exclusive scan over blocks (in place) + bin total
__global__ __launch_bounds__(256) void k_binsum(int* __restrict__ blockhist,
                                                int* __restrict__ bintot, int nb2) {
  __shared__ int s[256];
  __shared__ int carry;
  int t = threadIdx.x;
  if (t == 0) carry = 0;
  __syncthreads();
  int* row = blockhist + (size_t)blockIdx.x * nb2;
  for (int base = 0; base < nb2; base += 512) {
    int i0 = base + 2 * t, i1 = base + 2 * t + 1;
    int v0 = (i0 < nb2) ? row[i0] : 0;
    int v1 = (i1 < nb2) ? row[i1] : 0;
    int mySum = v0 + v1;
    s[t] = mySum;
    __syncthreads();
    for (int d = 1; d < 256; d <<= 1) {
      int u = (t >= d) ? s[t - d] : 0;
      __syncthreads();
      s[t] += u;
      __syncthreads();
    }
    int excl = s[t] - mySum + carry;
    if (i0 < nb2) row[i0] = excl;
    if (i1 < nb2) row[i1] = excl + v0;
    __syncthreads();
    if (t == 255) carry += s[255];
    __syncthreads();
  }
  if (t == 0) bintot[blockIdx.x] = carry;
}

// 3) exclusive scan of 256 bin totals (in place)
__global__ __launch_bounds__(256) void k_degscan(int* __restrict__ bintot) {
  __shared__ int s[256];
  int t = threadIdx.x;
  int v = bintot[t];
  s[t] = v;
  __syncthreads();
  for (int d = 1; d < 256; d <<= 1) {
    int u = (t >= d) ? s[t - d] : 0;
    __syncthreads();
    s[t] += u;
    __syncthreads();
  }
  bintot[t] = s[t] - v;
}

// 4) scatter: perm[binbase + blockbase + local rank] = node
__global__ __launch_bounds__(256) void k_scatter2(const int* __restrict__ counts,
                                                  const int* __restrict__ blockhist,
                                                  const int* __restrict__ binbase,
                                                  int* __restrict__ perm,
                                                  int N, int nb2) {
  __shared__ int h[256];
  int t = threadIdx.x;
  h[t] = 0;
  __syncthreads();
  int i = blockIdx.x * 256 + t;
  int d = 0, rank = 0;
  bool ok = (i < N);
  if (ok) {
    d = min(counts[i], 255);
    rank = atomicAdd(&h[d], 1);
  }
  __syncthreads();
  if (ok) {
    int base = binbase[d] + blockhist[d * nb2 + blockIdx.x];
    perm[base + rank] = i;
  }
}

// ---- CSR offsets + fill -----------------------------------------------------
__global__ __launch_bounds__(256) void k_scan1(const int* __restrict__ counts,
                                               int* __restrict__ offs,
                                               int* __restrict__ bsum, int N) {
  __shared__ int s[256];
  int t = threadIdx.x;
  int base = blockIdx.x * 1024 + t * 4;
  int c0 = 0, c1 = 0, c2 = 0, c3 = 0;
  if (base + 0 < N) c0 = counts[base + 0];
  if (base + 1 < N) c1 = counts[base + 1];
  if (base + 2 < N) c2 = counts[base + 2];
  if (base + 3 < N) c3 = counts[base + 3];
  int mySum = c0 + c1 + c2 + c3;
  s[t] = mySum;
  __syncthreads();
  for (int d = 1; d < 256; d <<= 1) {
    int v = (t >= d) ? s[t - d] : 0;
    __syncthreads();
    s[t] += v;
    __syncthreads();
  }
  int excl = s[t] - mySum;
  if (base + 0 < N) offs[base + 0] = excl;
  if (base + 1 < N) offs[base + 1] = excl + c0;
  if (base + 2 < N) offs[base + 2] = excl + c0 + c1;
  if (base + 3 < N) offs[base + 3] = excl + c0 + c1 + c2;
  if (t == 255) bsum[blockIdx.x] = s[255];
}

__global__ __launch_bounds__(128) void k_scan2(int* __restrict__ bsum, int nb) {
  __shared__ int s[128];
  int t = threadIdx.x;
  int v = (t < nb) ? bsum[t] : 0;
  s[t] = v;
  __syncthreads();
  for (int d = 1; d < 128; d <<= 1) {
    int u = (t >= d) ? s[t - d] : 0;
    __syncthreads();
    s[t] += u;
    __syncthreads();
  }
  if (t < nb) bsum[t] = s[t] - v;
}

__global__ __launch_bounds__(256) void k_scan3(int* __restrict__ offs,
                                               const int* __restrict__ bsum,
                                               int* __restrict__ cursor,
                                               int N, int E) {
  int t = threadIdx.x;
  int add = bsum[blockIdx.x];
  int base = blockIdx.x * 1024 + t * 4;
#pragma unroll
  for (int j = 0; j < 4; j++) {
    int i = base + j;
    if (i < N) { int v = offs[i] + add; offs[i] = v; cursor[i] = v; }
  }
  if (blockIdx.x == 0 && t == 0) offs[N] = E;
}

__global__ __launch_bounds__(256) void k_fill(const void* __restrict__ edges,
                                              const int* __restrict__ flag,
                                              int* __restrict__ cursor,
                                              int* __restrict__ csr, int E) {
  int e = blockIdx.x * 256 + threadIdx.x;
  if (e >= E) return;
  int s, d;
  if (*flag) {
    const int* p = (const int*)edges;
    s = p[e]; d = p[E + e];
  } else {
    const long long* p = (const long long*)edges;
    s = (int)p[e]; d = (int)p[E + e];
  }
  int pos = atomicAdd(&cursor[d], 1);
  csr[pos] = s;
}

// ---- W repack into MFMA B-fragment order (hi/lo split bf16) -----------------
__global__ __launch_bounds__(256) void k_repack(
    const float* __restrict__ W1, const float* __restrict__ W2,
    const float* __restrict__ W3,
    ushort_t* __restrict__ h1, ushort_t* __restrict__ l1,
    ushort_t* __restrict__ h2, ushort_t* __restrict__ l2,
    ushort_t* __restrict__ h3, ushort_t* __restrict__ l3) {
  int idx = blockIdx.x * 256 + threadIdx.x;
  const float* W; ushort_t* H; ushort_t* L; int NC; int i;
  if (idx < 16384)      { W = W1; H = h1; L = l1; NC = 128; i = idx; }
  else if (idx < 32768) { W = W2; H = h2; L = l2; NC = 128; i = idx - 16384; }
  else if (idx < 40960) { W = W3; H = h3; L = l3; NC = 64;  i = idx - 32768; }
  else return;
  int j = i & 7;
  int lane = (i >> 3) & 63;
  int NT = NC >> 4;
  int tile = (i >> 9) & (NT - 1);
  int ks = i >> (9 + (NC == 128 ? 3 : 2));
  int k = ks * 32 + (lane >> 4) * 8 + j;
  int n = tile * 16 + (lane & 15);
  float v = W[(size_t)k * NC + n];
  ushort_t hi = bf16_rne(v);
  ushort_t lo = bf16_rne(v - bf16_to_f32(hi));
  H[i] = hi; L[i] = lo;
}

// ---- layer 1 GEMM: Z(bf16)[M x NC] = A(fp32)[M x 128] @ W -------------------
template <int NC>
__global__ __launch_bounds__(256) void k_gemm_mfma(
    const float* __restrict__ A, const ushort_t* __restrict__ Bhi,
    const ushort_t* __restrict__ Blo, ushort_t* __restrict__ Z, int M) {
  constexpr int NT = NC / 16;
  int lane = threadIdx.x & 63;
  int wave = threadIdx.x >> 6;
  int row0 = blockIdx.x * 64 + wave * 16;
  int m = lane & 15;
  int q = lane >> 4;
  int grow = row0 + m;
  bool rowok = (grow < M);

  f32x4 acc[NT];
#pragma unroll
  for (int t = 0; t < NT; t++) { acc[t][0] = 0.f; acc[t][1] = 0.f; acc[t][2] = 0.f; acc[t][3] = 0.f; }

  const float* arow = A + (size_t)(rowok ? grow : 0) * 128 + q * 8;

#pragma unroll
  for (int ks = 0; ks < 4; ks++) {
    float av[8];
    *(float4*)(av)     = *(const float4*)(arow + ks * 32);
    *(float4*)(av + 4) = *(const float4*)(arow + ks * 32 + 4);
    short8 ahi, alo;
#pragma unroll
    for (int j = 0; j < 8; j++) {
      float v = av[j];
      ushort_t hi = bf16_rne(v);
      ahi[j] = (short)hi;
      alo[j] = (short)bf16_rne(v - bf16_to_f32(hi));
    }
#pragma unroll
    for (int t = 0; t < NT; t++) {
      const short8 bh = *(const short8*)(Bhi + (((size_t)ks * NT + t) * 64 + lane) * 8);
      const short8 bl = *(const short8*)(Blo + (((size_t)ks * NT + t) * 64 + lane) * 8);
      acc[t] = __builtin_amdgcn_mfma_f32_16x16x32_bf16(ahi, bh, acc[t], 0, 0, 0);
      acc[t] = __builtin_amdgcn_mfma_f32_16x16x32_bf16(ahi, bl, acc[t], 0, 0, 0);
      acc[t] = __builtin_amdgcn_mfma_f32_16x16x32_bf16(alo, bh, acc[t], 0, 0, 0);
    }
  }

  int zrow = row0 + q * 4;
#pragma unroll
  for (int r = 0; r < 4; r++) {
    if (zrow + r < M) {
#pragma unroll
      for (int t = 0; t < NT; t++)
        Z[(size_t)(zrow + r) * NC + t * 16 + m] = bf16_rne(acc[t][r]);
    }
  }
}

// ---- fused agg + GEMM (layers 2,3): degree-sorted via perm ------------------
template <int NC>
__global__ __launch_bounds__(256, 4) void k_fused(
    const ushort_t* __restrict__ Zin, const int* __restrict__ csr,
    const int* __restrict__ offs, const int* __restrict__ perm,
    const float* __restrict__ bias,
    const ushort_t* __restrict__ Bhi, const ushort_t* __restrict__ Blo,
    ushort_t* __restrict__ Zout, int M) {
  constexpr int NT = NC / 16;
  int lane = threadIdx.x & 63;
  int wave = threadIdx.x >> 6;
  int row0 = blockIdx.x * 64 + wave * 16;
  int m = lane & 15;
  int q = lane >> 4;
  int srow = row0 + m;                        // sorted index
  bool rowok = (srow < M);
  int node = perm[rowok ? srow : 0];          // original node id

  float av[4][8];
  const ushort_t* zr0 = Zin + (size_t)node * 128 + q * 8;
  const float* bq = bias + q * 8;
#pragma unroll
  for (int ks = 0; ks < 4; ks++) {
    float4 b0 = *(const float4*)(bq + ks * 32);
    float4 b1 = *(const float4*)(bq + ks * 32 + 4);
    short8 u = *(const short8*)(zr0 + ks * 32);
    av[ks][0] = b0.x + bf16_to_f32((ushort_t)u[0]);
    av[ks][1] = b0.y + bf16_to_f32((ushort_t)u[1]);
    av[ks][2] = b0.z + bf16_to_f32((ushort_t)u[2]);
    av[ks][3] = b0.w + bf16_to_f32((ushort_t)u[3]);
    av[ks][4] = b1.x + bf16_to_f32((ushort_t)u[4]);
    av[ks][5] = b1.y + bf16_to_f32((ushort_t)u[5]);
    av[ks][6] = b1.z + bf16_to_f32((ushort_t)u[6]);
    av[ks][7] = b1.w + bf16_to_f32((ushort_t)u[7]);
  }

  int s = 0, e = 0;
  if (rowok) { s = offs[node]; e = offs[node + 1]; }
  int j = s;
  for (; j + 2 <= e; j += 2) {
    int i0 = csr[j], i1 = csr[j + 1];
    const ushort_t* za = Zin + (size_t)i0 * 128 + q * 8;
    const ushort_t* zb = Zin + (size_t)i1 * 128 + q * 8;
    short8 ua[4], ub[4];
#pragma unroll
    for (int ks = 0; ks < 4; ks++) ua[ks] = *(const short8*)(za + ks * 32);
#pragma unroll
    for (int ks = 0; ks < 4; ks++) ub[ks] = *(const short8*)(zb + ks * 32);
#pragma unroll
    for (int ks = 0; ks < 4; ks++)
#pragma unroll
      for (int jj = 0; jj < 8; jj++)
        av[ks][jj] += bf16_to_f32((ushort_t)ua[ks][jj]) +
                      bf16_to_f32((ushort_t)ub[ks][jj]);
  }
  if (j < e) {
    int i0 = csr[j];
    const ushort_t* za = Zin + (size_t)i0 * 128 + q * 8;
#pragma unroll
    for (int ks = 0; ks < 4; ks++) {
      short8 u = *(const short8*)(za + ks * 32);
#pragma unroll
      for (int jj = 0; jj < 8; jj++)
        av[ks][jj] += bf16_to_f32((ushort_t)u[jj]);
    }
  }

  f32x4 acc[NT];
#pragma unroll
  for (int tt = 0; tt < NT; tt++) { acc[tt][0] = 0.f; acc[tt][1] = 0.f; acc[tt][2] = 0.f; acc[tt][3] = 0.f; }

#pragma unroll
  for (int ks = 0; ks < 4; ks++) {
    short8 ahi, alo;
#pragma unroll
    for (int jj = 0; jj < 8; jj++) {
      float v = fmaxf(av[ks][jj], 0.f);
      ushort_t hi = bf16_rne(v);
      ahi[jj] = (short)hi;
      alo[jj] = (short)bf16_rne(v - bf16_to_f32(hi));
    }
#pragma unroll
    for (int tt = 0; tt < NT; tt++) {
      const short8 bh = *(const short8*)(Bhi + (((size_t)ks * NT + tt) * 64 + lane) * 8);
      const short8 bl = *(const short8*)(Blo + (((size_t)ks * NT + tt) * 64 + lane) * 8);
      acc[tt] = __builtin_amdgcn_mfma_f32_16x16x32_bf16(ahi, bh, acc[tt], 0, 0, 0);
      acc[tt] = __builtin_amdgcn_mfma_f32_16x16x32_bf16(ahi, bl, acc[tt], 0, 0, 0);
      acc[tt] = __builtin_amdgcn_mfma_f32_16x16x32_bf16(alo, bh, acc[tt], 0, 0, 0);
    }
  }

  int sbase = row0 + q * 4;
#pragma unroll
  for (int r = 0; r < 4; r++) {
    if (sbase + r < M) {
      int prow = perm[sbase + r];
#pragma unroll
      for (int tt = 0; tt < NT; tt++)
        Zout[(size_t)prow * NC + tt * 16 + m] = bf16_rne(acc[tt][r]);
    }
  }
}

// ---- final agg (64 cols, bf16 z in, fp32 out), degree-sorted ----------------
__global__ __launch_bounds__(256) void k_agg64(const ushort_t* __restrict__ z,
                                               const int* __restrict__ csr,
                                               const int* __restrict__ offs,
                                               const int* __restrict__ perm,
                                               const float* __restrict__ bias,
                                               float* __restrict__ out, int N) {
  int t = threadIdx.x;
  int si = blockIdx.x * 32 + (t >> 3);
  if (si >= N) return;
  int node = perm[si];
  int c = (t & 7) * 8;
  float acc[8];
  {
    short8 u = *(const short8*)(z + (size_t)node * 64 + c);
#pragma unroll
    for (int jj = 0; jj < 8; jj++)
      acc[jj] = bias[c + jj] + bf16_to_f32((ushort_t)u[jj]);
  }
  int s = offs[node], e = offs[node + 1];
  int j = s;
  for (; j + 4 <= e; j += 4) {
    int i0 = csr[j], i1 = csr[j + 1], i2 = csr[j + 2], i3 = csr[j + 3];
    short8 u0 = *(const short8*)(z + (size_t)i0 * 64 + c);
    short8 u1 = *(const short8*)(z + (size_t)i1 * 64 + c);
    short8 u2 = *(const short8*)(z + (size_t)i2 * 64 + c);
    short8 u3 = *(const short8*)(z + (size_t)i3 * 64 + c);
#pragma unroll
    for (int jj = 0; jj < 8; jj++)
      acc[jj] += (bf16_to_f32((ushort_t)u0[jj]) + bf16_to_f32((ushort_t)u1[jj])) +
                 (bf16_to_f32((ushort_t)u2[jj]) + bf16_to_f32((ushort_t)u3[jj]));
  }
  for (; j < e; j++) {
    int i0 = csr[j];
    short8 u = *(const short8*)(z + (size_t)i0 * 64 + c);
#pragma unroll
    for (int jj = 0; jj < 8; jj++)
      acc[jj] += bf16_to_f32((ushort_t)u[jj]);
  }
  float4 o0 = make_float4(acc[0], acc[1], acc[2], acc[3]);
  float4 o1 = make_float4(acc[4], acc[5], acc[6], acc[7]);
  *(float4*)&out[(size_t)node * 64 + c]     = o0;
  *(float4*)&out[(size_t)node * 64 + c + 4] = o1;
}

// ---------------------------------------------------------------------------
extern "C" void kernel_launch(void* const* d_in, const int* in_sizes, int n_in,
                              void* d_out, int out_size, void* d_ws, size_t ws_size,
                              hipStream_t stream) {
  const float* x  = (const float*)d_in[0];
  const void* edges = d_in[1];
  const float* W1 = (const float*)d_in[2];
  const float* b1 = (const float*)d_in[3];
  const float* W2 = (const float*)d_in[4];
  const float* b2 = (const float*)d_in[5];
  const float* W3 = (const float*)d_in[6];
  const float* b3 = (const float*)d_in[7];
  float* out = (float*)d_out;

  int N = in_sizes[0] / 128;   // 100000
  int E = in_sizes[1] / 2;     // 600000

  char* w = (char*)d_ws;
  size_t off = 0;
  auto alloc = [&](size_t bytes) -> void* {
    void* p = w + off;
    off = (off + bytes + 255) & ~(size_t)255;
    return p;
  };
  int nb2 = (N + 255) / 256;                 // blocks for counting sort
  size_t curBytes = ((size_t)N * 4 + 255) & ~(size_t)255;
  int*   cursor = (int*)alloc(curBytes);     // degree counts, then fill cursor
  int*   flag   = (int*)alloc(4);            // adjacent: one memset covers both
  int*   blockhist = (int*)alloc((size_t)256 * nb2 * 4);
  int*   bintot = (int*)alloc(1024);
  int*   csr    = (int*)alloc((size_t)E * 4);
  int*   offs   = (int*)alloc((size_t)(N + 1) * 4);
  int*   perm   = (int*)alloc((size_t)N * 4);
  int*   bsum   = (int*)alloc(4096);
  ushort_t* h1  = (ushort_t*)alloc(16384 * 2);
  ushort_t* l1  = (ushort_t*)alloc(16384 * 2);
  ushort_t* h2  = (ushort_t*)alloc(16384 * 2);
  ushort_t* l2  = (ushort_t*)alloc(16384 * 2);
  ushort_t* h3  = (ushort_t*)alloc(8192 * 2);
  ushort_t* l3  = (ushort_t*)alloc(8192 * 2);
  ushort_t* z1  = (ushort_t*)alloc((size_t)N * 128 * 2);  // bf16
  ushort_t* z2  = (ushort_t*)alloc((size_t)N * 128 * 2);  // bf16
  ushort_t* z3  = z1;                                     // reuse (N x 64 fits)

  int ge = (E + 255) / 256;
  int nb = (N + 1023) / 1024;

  hipMemsetAsync(cursor, 0, curBytes + 4, stream);
  k_detect<<<4, 256, 0, stream>>>((const int*)edges, flag, E);
  k_hist<<<ge, 256, 0, stream>>>(edges, flag, cursor, E);
  // degree counting sort -- zero global atomics
  k_blockhist<<<nb2, 256, 0, stream>>>(cursor, blockhist, N, nb2);
  k_binsum<<<256, 256, 0, stream>>>(blockhist, bintot, nb2);
  k_degscan<<<1, 256, 0, stream>>>(bintot);
  k_scatter2<<<nb2, 256, 0, stream>>>(cursor, blockhist, bintot, perm, N, nb2);
  // CSR offsets + fill
  k_scan1<<<nb, 256, 0, stream>>>(cursor, offs, bsum, N);
  k_scan2<<<1, 128, 0, stream>>>(bsum, nb);
  k_scan3<<<nb, 256, 0, stream>>>(offs, bsum, cursor, N, E);
  k_fill<<<ge, 256, 0, stream>>>(edges, flag, cursor, csr, E);
  k_repack<<<160, 256, 0, stream>>>(W1, W2, W3, h1, l1, h2, l2, h3, l3);

  int gm = (N + 63) / 64;
  // layer 1: z1 = x @ W1   (bf16 out, natural order)
  k_gemm_mfma<128><<<gm, 256, 0, stream>>>(x, h1, l1, z1, N);
  // layer 2 fused: a1 = b1 + z1 + agg(z1) (regs); z2 = relu(a1) @ W2
  k_fused<128><<<gm, 256, 0, stream>>>(z1, csr, offs, perm, b1, h2, l2, z2, N);
  // layer 3 fused: a2 = b2 + z2 + agg(z2) (regs); z3 = relu(a2) @ W3
  k_fused<64><<<gm, 256, 0, stream>>>(z2, csr, offs, perm, b2, h3, l3, z3, N);
  // final agg: out = b3 + z3 + agg(z3)   (fp32 out)
  k_agg64<<<(N + 31) / 32, 256, 0, stream>>>(z3, csr, offs, perm, b3, out, N);
}